// Round 2
// baseline (109.874 us; speedup 1.0000x reference)
//
#include <hip/hip_runtime.h>
#include <hip/hip_bf16.h>

// Problem constants (from reference): B=32, L=128, D=48, R=64
#define PB 32
#define PL 128
#define PD 48
#define PR 64

// One block per (b, r) pair: grid = B*R = 2048 blocks, 256 threads (4 waves).
// Thread t -> lg = t>>6 (L-group 0..3), d = t&63 (active if d < 48).
// Each thread accumulates 32 consecutive l-steps for its fixed d, then a
// 4-way LDS reduction per d produces out[b, r, :].
// All tensors are float32 per the reference (round-1 post-mortem: reading
// them as bf16 produced inf — garbage exponents overflowed h).
__global__ __launch_bounds__(256) void alnn_kernel(
    const float* __restrict__ X,
    const float* __restrict__ T,
    const float* __restrict__ M,
    const float* __restrict__ DT,
    const float* __restrict__ P,
    const float* __restrict__ alpha,
    const float* __restrict__ w_t,
    const float* __restrict__ b_t,
    const float* __restrict__ w_v,
    const float* __restrict__ b_v,
    float* __restrict__ out)
{
    const int bid = blockIdx.x;
    const int r = bid & (PR - 1);   // grid laid out as b*R + r
    const int b = bid >> 6;
    const int t = threadIdx.x;
    const int lg = t >> 6;          // 0..3
    const int d  = t & 63;          // 0..63; lanes 48..63 idle (25% waste, fine)

    __shared__ float part[4][PD];

    // alpha[r] broadcast; relu(alpha)
    float ar = alpha[r];
    ar = ar > 0.0f ? ar : 0.0f;
    // linspace(0, 48, 64): ref_r = 48 * r / 63
    const float refr = 48.0f * (float)r / 63.0f;

    float acc = 0.0f;
    if (d < PD) {
        const int in_base = b * (PL * PD);        // X/T/M/DT/P slice for batch b
        const int wt_base = r * (PL * PD * 5);    // w_t slice for rank r
        const int rv_base = r * (PL * PD);        // b_t / w_v slice for rank r
        #pragma unroll 4
        for (int li = 0; li < 32; ++li) {
            const int l  = lg * 32 + li;
            const int id = in_base + l * PD + d;
            const float x  = X[id];
            const float tt = T[id];
            const float m  = M[id];
            const float dt = DT[id];
            const float p  = P[id];

            const float dist = fabsf(tt - refr);
            const float kern = __expf(-ar * dist);
            float inten = x * kern;
            inten = inten > 0.0f ? inten : 0.0f;

            const int wi = wt_base + l * (PD * 5) + d * 5;
            const int vi = rv_base + l * PD + d;
            float h = w_t[wi + 0] * x
                    + w_t[wi + 1] * inten
                    + w_t[wi + 2] * m
                    + w_t[wi + 3] * dt
                    + w_t[wi + 4] * p
                    + 5.0f * b_t[vi];   // b_t broadcast over 5-axis then summed
            h = h > 0.0f ? h : 0.0f;

            acc += w_v[vi] * h;
        }
        part[lg][d] = acc;
    }
    __syncthreads();

    if (lg == 0 && d < PD) {
        float s = part[0][d] + part[1][d] + part[2][d] + part[3][d]
                + 128.0f * b_v[r * PD + d];  // b_v broadcast over L then summed
        s = s > 0.0f ? s : 0.0f;
        out[b * (PR * PD) + r * PD + d] = s;
    }
}

extern "C" void kernel_launch(void* const* d_in, const int* in_sizes, int n_in,
                              void* d_out, int out_size, void* d_ws, size_t ws_size,
                              hipStream_t stream) {
    // setup_inputs() order: X, T, M, DT, P, alpha, w_t, b_t, w_v, b_v (all f32)
    const float* X     = (const float*)d_in[0];
    const float* T     = (const float*)d_in[1];
    const float* M     = (const float*)d_in[2];
    const float* DT    = (const float*)d_in[3];
    const float* P     = (const float*)d_in[4];
    const float* alpha = (const float*)d_in[5];
    const float* w_t   = (const float*)d_in[6];
    const float* b_t   = (const float*)d_in[7];
    const float* w_v   = (const float*)d_in[8];
    const float* b_v   = (const float*)d_in[9];
    float* out = (float*)d_out;

    alnn_kernel<<<PB * PR, 256, 0, stream>>>(X, T, M, DT, P, alpha, w_t, b_t, w_v, b_v, out);
}

// Round 3
// 108.981 us; speedup vs baseline: 1.0082x; 1.0082x over previous
//
#include <hip/hip_runtime.h>
#include <hip/hip_bf16.h>

// Problem constants (from reference): B=32, L=128, D=48, R=64
#define PB 32
#define PL 128
#define PD 48
#define PR 64

// One block per (b, r): grid = 2048 blocks, 192 threads (3 waves).
// tid -> lg = tid/12 (L-group, 0..15), dq = tid%12 (d-quad, 0..11).
// Each thread accumulates 8 L-steps (l = li*16 + lg), handling 4 consecutive
// d per step via float4 loads (12 float4 loads per 4 elements vs 48 scalar
// loads in round 2 -> 4x fewer VMEM instructions; all lanes active).
// All float4 accesses are 16B-aligned: dq*16B for D-major tensors, dq*80B
// for w_t (stride-5 innermost).
__global__ __launch_bounds__(192) void alnn_kernel(
    const float* __restrict__ X,
    const float* __restrict__ T,
    const float* __restrict__ M,
    const float* __restrict__ DT,
    const float* __restrict__ P,
    const float* __restrict__ alpha,
    const float* __restrict__ w_t,
    const float* __restrict__ b_t,
    const float* __restrict__ w_v,
    const float* __restrict__ b_v,
    float* __restrict__ out)
{
    const int bid = blockIdx.x;
    const int r = bid & (PR - 1);   // grid laid out as b*R + r
    const int b = bid >> 6;
    const int tid = threadIdx.x;
    const int lg = tid / 12;        // 0..15
    const int dq = tid - lg * 12;   // 0..11

    __shared__ float4 part[16][12];

    float ar = alpha[r];
    ar = ar > 0.0f ? ar : 0.0f;
    const float refr = 48.0f * (float)r / 63.0f;   // linspace(0,48,64)

    const int in_base = b * (PL * PD) + dq * 4;        // X/T/M/DT/P
    const int wt_base = r * (PL * PD * 5) + dq * 20;   // w_t
    const int rv_base = r * (PL * PD) + dq * 4;        // b_t / w_v

    float acc[4] = {0.0f, 0.0f, 0.0f, 0.0f};

    #pragma unroll
    for (int li = 0; li < 8; ++li) {
        const int l = li * 16 + lg;   // interleaved so a wave reads adjacent rows
        const int io = in_base + l * PD;
        const float4 x4  = *(const float4*)(X  + io);
        const float4 t4  = *(const float4*)(T  + io);
        const float4 m4  = *(const float4*)(M  + io);
        const float4 dt4 = *(const float4*)(DT + io);
        const float4 p4  = *(const float4*)(P  + io);

        const float* wp = w_t + wt_base + l * (PD * 5);
        float w[20];
        *(float4*)(w +  0) = *(const float4*)(wp +  0);
        *(float4*)(w +  4) = *(const float4*)(wp +  4);
        *(float4*)(w +  8) = *(const float4*)(wp +  8);
        *(float4*)(w + 12) = *(const float4*)(wp + 12);
        *(float4*)(w + 16) = *(const float4*)(wp + 16);

        const int vo = rv_base + l * PD;
        const float4 bt4 = *(const float4*)(b_t + vo);
        const float4 wv4 = *(const float4*)(w_v + vo);

        const float xs[4]  = {x4.x,  x4.y,  x4.z,  x4.w};
        const float ts[4]  = {t4.x,  t4.y,  t4.z,  t4.w};
        const float ms[4]  = {m4.x,  m4.y,  m4.z,  m4.w};
        const float dts[4] = {dt4.x, dt4.y, dt4.z, dt4.w};
        const float ps[4]  = {p4.x,  p4.y,  p4.z,  p4.w};
        const float bts[4] = {bt4.x, bt4.y, bt4.z, bt4.w};
        const float wvs[4] = {wv4.x, wv4.y, wv4.z, wv4.w};

        #pragma unroll
        for (int j = 0; j < 4; ++j) {
            const float x = xs[j];
            const float dist = fabsf(ts[j] - refr);
            const float kern = __expf(-ar * dist);
            float inten = x * kern;
            inten = inten > 0.0f ? inten : 0.0f;
            float h = w[j*5 + 0] * x
                    + w[j*5 + 1] * inten
                    + w[j*5 + 2] * ms[j]
                    + w[j*5 + 3] * dts[j]
                    + w[j*5 + 4] * ps[j]
                    + 5.0f * bts[j];          // b_t broadcast over 5-axis
            h = h > 0.0f ? h : 0.0f;
            acc[j] += wvs[j] * h;
        }
    }

    part[lg][dq] = make_float4(acc[0], acc[1], acc[2], acc[3]);
    __syncthreads();

    if (tid < 12) {
        float4 s = part[0][tid];
        #pragma unroll
        for (int g = 1; g < 16; ++g) {
            const float4 q = part[g][tid];
            s.x += q.x; s.y += q.y; s.z += q.z; s.w += q.w;
        }
        const float4 bv4 = *(const float4*)(b_v + r * PD + tid * 4);
        s.x = fmaxf(s.x + 128.0f * bv4.x, 0.0f);   // b_v broadcast over L
        s.y = fmaxf(s.y + 128.0f * bv4.y, 0.0f);
        s.z = fmaxf(s.z + 128.0f * bv4.z, 0.0f);
        s.w = fmaxf(s.w + 128.0f * bv4.w, 0.0f);
        *(float4*)(out + b * (PR * PD) + r * PD + tid * 4) = s;
    }
}

extern "C" void kernel_launch(void* const* d_in, const int* in_sizes, int n_in,
                              void* d_out, int out_size, void* d_ws, size_t ws_size,
                              hipStream_t stream) {
    // setup_inputs() order: X, T, M, DT, P, alpha, w_t, b_t, w_v, b_v (all f32)
    const float* X     = (const float*)d_in[0];
    const float* T     = (const float*)d_in[1];
    const float* M     = (const float*)d_in[2];
    const float* DT    = (const float*)d_in[3];
    const float* P     = (const float*)d_in[4];
    const float* alpha = (const float*)d_in[5];
    const float* w_t   = (const float*)d_in[6];
    const float* b_t   = (const float*)d_in[7];
    const float* w_v   = (const float*)d_in[8];
    const float* b_v   = (const float*)d_in[9];
    float* out = (float*)d_out;

    alnn_kernel<<<PB * PR, 192, 0, stream>>>(X, T, M, DT, P, alpha, w_t, b_t, w_v, b_v, out);
}

// Round 4
// 101.181 us; speedup vs baseline: 1.0859x; 1.0771x over previous
//
#include <hip/hip_runtime.h>
#include <hip/hip_bf16.h>

// Problem constants (from reference): B=32, L=128, D=48, R=64
#define PB 32
#define PL 128
#define PD 48
#define PR 64

// Register-tiled: one block per (2 b's x 2 r's) -> grid = 16*32 = 512 blocks,
// 192 threads (3 waves). tid -> lg = tid/12 (L-group 0..15), dq = tid%12
// (d-quad). Per l-step a thread loads 10 input float4s (5 tensors x 2 b),
// 10 w_t float4s (5 x 2 r) and 4 b_t/w_v float4s (2 x 2 r) and computes
// 2x2x4 = 16 h-elements: 6 floats loaded per element vs 12 in round 3 ->
// halves VMEM instruction count and L2 demand traffic (~604 -> ~302 MB).
// 512 blocks = 2 blocks/CU, 6 waves/CU.
__device__ __forceinline__ void compute4(
    const float4 x4, const float4 t4, const float4 m4, const float4 dt4,
    const float4 p4, const float* __restrict__ w20, const float4 bt4,
    const float4 wv4, const float ar, const float refr, float4& acc)
{
    const float xs[4]  = {x4.x,  x4.y,  x4.z,  x4.w};
    const float ts[4]  = {t4.x,  t4.y,  t4.z,  t4.w};
    const float ms[4]  = {m4.x,  m4.y,  m4.z,  m4.w};
    const float dts[4] = {dt4.x, dt4.y, dt4.z, dt4.w};
    const float ps[4]  = {p4.x,  p4.y,  p4.z,  p4.w};
    const float bts[4] = {bt4.x, bt4.y, bt4.z, bt4.w};
    const float wvs[4] = {wv4.x, wv4.y, wv4.z, wv4.w};
    float a[4] = {acc.x, acc.y, acc.z, acc.w};
    #pragma unroll
    for (int j = 0; j < 4; ++j) {
        const float x = xs[j];
        const float dist = fabsf(ts[j] - refr);
        const float kern = __expf(-ar * dist);
        float inten = x * kern;
        inten = inten > 0.0f ? inten : 0.0f;
        float h = w20[j*5 + 0] * x
                + w20[j*5 + 1] * inten
                + w20[j*5 + 2] * ms[j]
                + w20[j*5 + 3] * dts[j]
                + w20[j*5 + 4] * ps[j]
                + 5.0f * bts[j];              // b_t broadcast over 5-axis
        h = h > 0.0f ? h : 0.0f;
        a[j] += wvs[j] * h;
    }
    acc = make_float4(a[0], a[1], a[2], a[3]);
}

__global__ __launch_bounds__(192) void alnn_kernel(
    const float* __restrict__ X,
    const float* __restrict__ T,
    const float* __restrict__ M,
    const float* __restrict__ DT,
    const float* __restrict__ P,
    const float* __restrict__ alpha,
    const float* __restrict__ w_t,
    const float* __restrict__ b_t,
    const float* __restrict__ w_v,
    const float* __restrict__ b_v,
    float* __restrict__ out)
{
    const int bid = blockIdx.x;
    const int rrb = bid & 31;       // r-tile index 0..31
    const int bbb = bid >> 5;       // b-tile index 0..15
    const int r0 = rrb * 2;
    const int b0 = bbb * 2;
    const int tid = threadIdx.x;
    const int lg = tid / 12;        // 0..15
    const int dq = tid - lg * 12;   // 0..11

    // +1 float4 pad breaks the stride-48 (=0 mod 32 banks) reduction pattern
    __shared__ float4 part[16][49];

    const float ar0 = fmaxf(alpha[r0], 0.0f);
    const float ar1 = fmaxf(alpha[r0 + 1], 0.0f);
    const float refr0 = 48.0f * (float)r0 / 63.0f;        // linspace(0,48,64)
    const float refr1 = 48.0f * (float)(r0 + 1) / 63.0f;

    int io = b0 * (PL * PD) + lg * PD + dq * 4;           // X/T/M/DT/P, b0
    int wo = r0 * (PL * PD * 5) + lg * (PD * 5) + dq * 20; // w_t, r0
    int vo = r0 * (PL * PD) + lg * PD + dq * 4;           // b_t/w_v, r0

    float4 acc00 = make_float4(0.f, 0.f, 0.f, 0.f);  // (b0, r0)
    float4 acc01 = make_float4(0.f, 0.f, 0.f, 0.f);  // (b0, r1)
    float4 acc10 = make_float4(0.f, 0.f, 0.f, 0.f);  // (b1, r0)
    float4 acc11 = make_float4(0.f, 0.f, 0.f, 0.f);  // (b1, r1)

    #pragma unroll 2
    for (int li = 0; li < 8; ++li) {
        // inputs for b0, b1
        const float4 x0  = *(const float4*)(X  + io);
        const float4 t0  = *(const float4*)(T  + io);
        const float4 m0  = *(const float4*)(M  + io);
        const float4 dt0 = *(const float4*)(DT + io);
        const float4 p0  = *(const float4*)(P  + io);
        const float4 x1  = *(const float4*)(X  + io + PL * PD);
        const float4 t1  = *(const float4*)(T  + io + PL * PD);
        const float4 m1  = *(const float4*)(M  + io + PL * PD);
        const float4 dt1 = *(const float4*)(DT + io + PL * PD);
        const float4 p1  = *(const float4*)(P  + io + PL * PD);

        // w_t for r0, r1 (20 contiguous floats each)
        float w0[20], w1[20];
        #pragma unroll
        for (int q = 0; q < 5; ++q) {
            *(float4*)(w0 + q * 4) = *(const float4*)(w_t + wo + q * 4);
            *(float4*)(w1 + q * 4) = *(const float4*)(w_t + wo + PL * PD * 5 + q * 4);
        }

        const float4 bt0 = *(const float4*)(b_t + vo);
        const float4 wv0 = *(const float4*)(w_v + vo);
        const float4 bt1 = *(const float4*)(b_t + vo + PL * PD);
        const float4 wv1 = *(const float4*)(w_v + vo + PL * PD);

        compute4(x0, t0, m0, dt0, p0, w0, bt0, wv0, ar0, refr0, acc00);
        compute4(x0, t0, m0, dt0, p0, w1, bt1, wv1, ar1, refr1, acc01);
        compute4(x1, t1, m1, dt1, p1, w0, bt0, wv0, ar0, refr0, acc10);
        compute4(x1, t1, m1, dt1, p1, w1, bt1, wv1, ar1, refr1, acc11);

        io += 16 * PD;        // l advances by 16
        wo += 16 * PD * 5;
        vo += 16 * PD;
    }

    // stage partials: o = bi*24 + ri*12 + dq
    part[lg][ 0 + dq] = acc00;
    part[lg][12 + dq] = acc01;
    part[lg][24 + dq] = acc10;
    part[lg][36 + dq] = acc11;
    __syncthreads();

    if (tid < 48) {
        const int o = tid;
        const int bi = o / 24;            // 0..1
        const int ri = (o - bi * 24) / 12; // 0..1
        const int dqo = o - bi * 24 - ri * 12;
        float4 s = part[0][o];
        #pragma unroll
        for (int g = 1; g < 16; ++g) {
            const float4 q = part[g][o];
            s.x += q.x; s.y += q.y; s.z += q.z; s.w += q.w;
        }
        const int r = r0 + ri;
        const int b = b0 + bi;
        const float4 bv4 = *(const float4*)(b_v + r * PD + dqo * 4);
        s.x = fmaxf(s.x + 128.0f * bv4.x, 0.0f);   // b_v broadcast over L
        s.y = fmaxf(s.y + 128.0f * bv4.y, 0.0f);
        s.z = fmaxf(s.z + 128.0f * bv4.z, 0.0f);
        s.w = fmaxf(s.w + 128.0f * bv4.w, 0.0f);
        *(float4*)(out + b * (PR * PD) + r * PD + dqo * 4) = s;
    }
}

extern "C" void kernel_launch(void* const* d_in, const int* in_sizes, int n_in,
                              void* d_out, int out_size, void* d_ws, size_t ws_size,
                              hipStream_t stream) {
    // setup_inputs() order: X, T, M, DT, P, alpha, w_t, b_t, w_v, b_v (all f32)
    const float* X     = (const float*)d_in[0];
    const float* T     = (const float*)d_in[1];
    const float* M     = (const float*)d_in[2];
    const float* DT    = (const float*)d_in[3];
    const float* P     = (const float*)d_in[4];
    const float* alpha = (const float*)d_in[5];
    const float* w_t   = (const float*)d_in[6];
    const float* b_t   = (const float*)d_in[7];
    const float* w_v   = (const float*)d_in[8];
    const float* b_v   = (const float*)d_in[9];
    float* out = (float*)d_out;

    alnn_kernel<<<512, 192, 0, stream>>>(X, T, M, DT, P, alpha, w_t, b_t, w_v, b_v, out);
}